// Round 10
// baseline (45.333 us; speedup 1.0000x reference)
//
#include <hip/hip_runtime.h>
#include <math.h>

#define NQ 8
#define FDIM 2048
#define EPSV 1e-5f

typedef __attribute__((ext_vector_type(8))) short short8v;   // 8 bf16 = 4 VGPR
typedef __attribute__((ext_vector_type(16))) float f32x16;   // 32x32 C/D frag

__device__ __forceinline__ unsigned pk_bf16(float lo, float hi) {
    unsigned r;
    asm("v_cvt_pk_bf16_f32 %0, %1, %2" : "=v"(r) : "v"(lo), "v"(hi));
    return r;
}

__device__ __forceinline__ short8v pack4(unsigned a, unsigned b, unsigned c, unsigned d) {
    uint4 w; w.x = a; w.y = b; w.z = c; w.w = d;
    return __builtin_bit_cast(short8v, w);
}

#define MFMA32 __builtin_amdgcn_mfma_f32_32x32x16_bf16

// relu + bf16 repack of a 32x32 C1 fragment into two GEMM2 A-frags
#define RP(C, d0, d1)                                                   \
  d0 = pack4(pk_bf16(fmaxf(C[0], 0.f),  fmaxf(C[1], 0.f)),              \
             pk_bf16(fmaxf(C[2], 0.f),  fmaxf(C[3], 0.f)),              \
             pk_bf16(fmaxf(C[4], 0.f),  fmaxf(C[5], 0.f)),              \
             pk_bf16(fmaxf(C[6], 0.f),  fmaxf(C[7], 0.f)));             \
  d1 = pack4(pk_bf16(fmaxf(C[8], 0.f),  fmaxf(C[9], 0.f)),              \
             pk_bf16(fmaxf(C[10], 0.f), fmaxf(C[11], 0.f)),             \
             pk_bf16(fmaxf(C[12], 0.f), fmaxf(C[13], 0.f)),             \
             pk_bf16(fmaxf(C[14], 0.f), fmaxf(C[15], 0.f)))

// R10 DIAGNOSTIC: R9 structure, k-loop run 3x (acc accumulates 3x the partial,
// scaled by 1/3 in the epilogue). Purpose: raise dur above the harness's 38us
// fill kernels so this kernel lands in the rocprof top-5 with full counters,
// and (dur - 22.5)/2 isolates the pure k-loop share from staging/prologue.
#define ITER(AUSE, ALOAD, B0USE, B1USE, C2IDX)                          \
  {                                                                     \
    short8v p00, p01, p10, p11;                                         \
    RP(C1_0, p00, p01); RP(C1_1, p10, p11);                             \
    C1_0 = MFMA32(AUSE, b1S0, zeroC, 0, 0, 0);                          \
    C1_1 = MFMA32(AUSE, b1S1, zeroC, 0, 0, 0);                          \
    acc0 = MFMA32(p00, B0USE, acc0, 0, 0, 0);                           \
    acc1 = MFMA32(p10, B0USE, acc1, 0, 0, 0);                           \
    acc0 = MFMA32(p01, B1USE, acc0, 0, 0, 0);                           \
    acc1 = MFMA32(p11, B1USE, acc1, 0, 0, 0);                           \
    short8v p20, p21, p30, p31;                                         \
    RP(C1_2, p20, p21); RP(C1_3, p30, p31);                             \
    C1_2 = MFMA32(AUSE, b1S2, zeroC, 0, 0, 0);                          \
    C1_3 = MFMA32(AUSE, b1S3, zeroC, 0, 0, 0);                          \
    acc2 = MFMA32(p20, B0USE, acc2, 0, 0, 0);                           \
    acc3 = MFMA32(p30, B0USE, acc3, 0, 0, 0);                           \
    acc2 = MFMA32(p21, B1USE, acc2, 0, 0, 0);                           \
    acc3 = MFMA32(p31, B1USE, acc3, 0, 0, 0);                           \
    ALOAD = *reinterpret_cast<const short8v*>(W1p + (C2IDX) * 512);     \
    B0USE = *reinterpret_cast<const short8v*>(W2p + (C2IDX) * 32);      \
    B1USE = *reinterpret_cast<const short8v*>(W2p + (C2IDX) * 32 + 16); \
  }

__launch_bounds__(512, 2)
__global__ void qtb_kernel(const float* __restrict__ x,
                           const float* __restrict__ theta,
                           const float* __restrict__ phi,
                           const float* __restrict__ W1,
                           const float* __restrict__ b1,
                           const float* __restrict__ W2,
                           const float* __restrict__ b2,
                           const float* __restrict__ g1,
                           const float* __restrict__ be1,
                           const float* __restrict__ g2,
                           const float* __restrict__ be2,
                           float* __restrict__ out)
{
    __shared__ short W1f[64 * 512];    // A-frag order, 64 KB
    __shared__ short W2s[8 * 2056];    // quad-permuted k, ~32 KB
    __shared__ float park[8][1024];    // per-wave partial f (128 tok x 8), 32 KB
    __shared__ float hLds[256 * 8];    // h parked across the loop, 8 KB

    const int tid = threadIdx.x;

    // ---- stage W1(+b1) into A-fragment order (4 iters) ----
    for (int k = tid; k < FDIM; k += 512) {
        const float4 wa = *reinterpret_cast<const float4*>(W1 + (size_t)k * NQ);
        const float4 wb = *reinterpret_cast<const float4*>(W1 + (size_t)k * NQ + 4);
        const float bk = b1[k];
        unsigned* d0 = reinterpret_cast<unsigned*>(&W1f[(k >> 5) * 512 + (k & 31) * 8]);
        unsigned* d1 = reinterpret_cast<unsigned*>(&W1f[(k >> 5) * 512 + ((k & 31) + 32) * 8]);
        d0[0] = pk_bf16(wa.x, wa.y); d0[1] = pk_bf16(wa.z, wa.w);
        d0[2] = pk_bf16(bk, 0.f);    d0[3] = 0u;
        d1[0] = pk_bf16(wb.x, wb.y); d1[1] = pk_bf16(wb.z, wb.w);
        d1[2] = 0u;                  d1[3] = 0u;
    }
    // ---- stage W2 bf16 per quad (float4 -> ds_write_b64, 8 iters) ----
    for (int idx = tid; idx < 8 * 512; idx += 512) {
        const int i = idx >> 9, kq = idx & 511;
        const int k0 = kq * 4;
        const float4 w = *reinterpret_cast<const float4*>(W2 + (size_t)i * FDIM + k0);
        const int quad = (k0 >> 2) & 3;
        const int posq = (0x3120 >> (quad * 4)) & 0xF;   // 0->0,1->2,2->1,3->3
        const int dcol = (k0 & ~15) | (posq * 4);
        uint2 pkw; pkw.x = pk_bf16(w.x, w.y); pkw.y = pk_bf16(w.z, w.w);
        *reinterpret_cast<uint2*>(&W2s[i * 2056 + dcol]) = pkw;
    }
    __syncthreads();

    const int lane = tid & 63;
    const int wid  = tid >> 6;      // 0..7
    const int g    = wid & 1;       // token half (128 tokens)
    const int q    = wid >> 1;      // f-quarter 0..3
    const int hi2  = lane >> 5;
    const int il   = lane & 31;
    const int tbase = blockIdx.x * 256 + g * 128;

    // ---- per-token prologue: 2 tokens per lane ----
    float h[2][8];
    unsigned zpkt[2][4];
#pragma unroll
    for (int tt = 0; tt < 2; ++tt) {
        const int token = tbase + tt * 64 + lane;
        const float4 xa = reinterpret_cast<const float4*>(x + (size_t)token * NQ)[0];
        const float4 xb = reinterpret_cast<const float4*>(x + (size_t)token * NQ)[1];
        const float xv[8] = {xa.x, xa.y, xa.z, xa.w, xb.x, xb.y, xb.z, xb.w};

        float c[8];
#pragma unroll
        for (int j = 0; j < 8; ++j) c[j] = __cosf(xv[j] + theta[j]);
        float attn[8];
        attn[0] = ((c[1] * c[2]) * (c[3] * c[4])) * ((c[5] * c[6]) * c[7]);
        {
            float p = c[0];
#pragma unroll
            for (int j = 1; j < 8; ++j) { p *= c[j]; attn[j] = p; }
        }
        float s[8];
#pragma unroll
        for (int j = 0; j < 8; ++j) s[j] = xv[j] + attn[j];
        float mean = 0.f;
#pragma unroll
        for (int j = 0; j < 8; ++j) mean += s[j];
        mean *= 0.125f;
        float var = 0.f;
#pragma unroll
        for (int j = 0; j < 8; ++j) { float d = s[j] - mean; var = fmaf(d, d, var); }
        var *= 0.125f;
        const float rs = rsqrtf(var + EPSV);
#pragma unroll
        for (int j = 0; j < 8; ++j) h[tt][j] = (s[j] - mean) * rs * g1[j] + be1[j];

        float zv[8];
#pragma unroll
        for (int j = 0; j < 8; ++j) zv[j] = __cosf(phi[j]) * __cosf(h[tt][j]);
#pragma unroll
        for (int p = 0; p < 4; ++p) zpkt[tt][p] = pk_bf16(zv[2 * p], zv[2 * p + 1]);
    }

    // park h (combine waves q==0 reload after the loop)
    if (q == 0) {
        float4* hp0 = reinterpret_cast<float4*>(&hLds[(g * 128 + lane) * 8]);
        hp0[0] = make_float4(h[0][0], h[0][1], h[0][2], h[0][3]);
        hp0[1] = make_float4(h[0][4], h[0][5], h[0][6], h[0][7]);
        float4* hp1 = reinterpret_cast<float4*>(&hLds[(g * 128 + 64 + lane) * 8]);
        hp1[0] = make_float4(h[1][0], h[1][1], h[1][2], h[1][3]);
        hp1[1] = make_float4(h[1][4], h[1][5], h[1][6], h[1][7]);
    }

    // ---- z B-fragments for 4 token-subtiles ----
    unsigned zs[2][2][4];
#pragma unroll
    for (int tt = 0; tt < 2; ++tt)
#pragma unroll
        for (int p = 0; p < 4; ++p) {
            zs[tt][0][p] = (unsigned)__shfl((int)zpkt[tt][p], il);
            zs[tt][1][p] = (unsigned)__shfl((int)zpkt[tt][p], 32 + il);
        }
    const unsigned biasv = 0x00003f80u;  // bf16(1.0) low half
    const short8v b1S0 = pack4(hi2 ? zs[0][0][2] : zs[0][0][0],
                               hi2 ? zs[0][0][3] : zs[0][0][1],
                               hi2 ? 0u : biasv, 0u);
    const short8v b1S1 = pack4(hi2 ? zs[0][1][2] : zs[0][1][0],
                               hi2 ? zs[0][1][3] : zs[0][1][1],
                               hi2 ? 0u : biasv, 0u);
    const short8v b1S2 = pack4(hi2 ? zs[1][0][2] : zs[1][0][0],
                               hi2 ? zs[1][0][3] : zs[1][0][1],
                               hi2 ? 0u : biasv, 0u);
    const short8v b1S3 = pack4(hi2 ? zs[1][1][2] : zs[1][1][0],
                               hi2 ? zs[1][1][3] : zs[1][1][1],
                               hi2 ? 0u : biasv, 0u);

    f32x16 zeroC;
#pragma unroll
    for (int e = 0; e < 16; ++e) zeroC[e] = 0.f;
    f32x16 acc0 = zeroC, acc1 = zeroC, acc2 = zeroC, acc3 = zeroC;

    const int ir = il & 7;
    const int lo = q * 16;

    const short* W1p = &W1f[lane * 8];
    const short* W2p = &W2s[ir * 2056 + hi2 * 8];

    // ---- DIAGNOSTIC: run the k-loop 3x; acc accumulates 3x the partial.
    // Every rep feeds the final acc value -> no DCE. Scaled by 1/3 below.
#pragma unroll 1
    for (int rep = 0; rep < 3; ++rep) {
        // pipeline prologue: C1 gen 0 in flight; tiles 0 and 1 resident
        short8v A1a = *reinterpret_cast<const short8v*>(W1p + lo * 512);
        short8v B0a = *reinterpret_cast<const short8v*>(W2p + lo * 32);
        short8v B1a = *reinterpret_cast<const short8v*>(W2p + lo * 32 + 16);
        f32x16 C1_0 = MFMA32(A1a, b1S0, zeroC, 0, 0, 0);
        f32x16 C1_1 = MFMA32(A1a, b1S1, zeroC, 0, 0, 0);
        f32x16 C1_2 = MFMA32(A1a, b1S2, zeroC, 0, 0, 0);
        f32x16 C1_3 = MFMA32(A1a, b1S3, zeroC, 0, 0, 0);
        short8v A1b = *reinterpret_cast<const short8v*>(W1p + (lo + 1) * 512);
        short8v B0b = *reinterpret_cast<const short8v*>(W2p + (lo + 1) * 32);
        short8v B1b = *reinterpret_cast<const short8v*>(W2p + (lo + 1) * 32 + 16);

#pragma unroll 1
        for (int t = 0; t < 16; t += 2) {
            ITER(A1b, A1a, B0a, B1a, lo + ((t + 2) & 15));
            ITER(A1a, A1b, B0b, B1b, lo + ((t + 3) & 15));
        }
    }

    // ---- park partial f (cols<8) ----
    if (il < 8) {
        float* fb = &park[wid][0];
#pragma unroll
        for (int r = 0; r < 16; ++r) {
            const int trow = (r & 3) + 8 * (r >> 2) + 4 * hi2;
            fb[trow * 8 + il]         = acc0[r];
            fb[(32 + trow) * 8 + il]  = acc1[r];
            fb[(64 + trow) * 8 + il]  = acc2[r];
            fb[(96 + trow) * 8 + il]  = acc3[r];
        }
    }
    __syncthreads();

    // ---- combine + LN2 + store: waves q==0, 2 tokens per lane ----
    if (q == 0) {
        const float repScale = 1.0f / 3.0f;   // undo the 3x diagnostic reps
#pragma unroll
        for (int tt = 0; tt < 2; ++tt) {
            const int tloc = tt * 64 + lane;
            float fv[8] = {0.f, 0.f, 0.f, 0.f, 0.f, 0.f, 0.f, 0.f};
#pragma unroll
            for (int qq = 0; qq < 4; ++qq) {
                const float* pb = &park[qq * 2 + g][tloc * 8];
                const float4 f0 = *reinterpret_cast<const float4*>(pb);
                const float4 f1 = *reinterpret_cast<const float4*>(pb + 4);
                fv[0] += f0.x; fv[1] += f0.y; fv[2] += f0.z; fv[3] += f0.w;
                fv[4] += f1.x; fv[5] += f1.y; fv[6] += f1.z; fv[7] += f1.w;
            }

            const float4 h0 = reinterpret_cast<const float4*>(&hLds[(g * 128 + tloc) * 8])[0];
            const float4 h1 = reinterpret_cast<const float4*>(&hLds[(g * 128 + tloc) * 8])[1];
            const float hv[8] = {h0.x, h0.y, h0.z, h0.w, h1.x, h1.y, h1.z, h1.w};

            float y[8];
#pragma unroll
            for (int j = 0; j < 8; ++j) y[j] = hv[j] + fv[j] * repScale + b2[j];
            float mean2 = 0.f;
#pragma unroll
            for (int j = 0; j < 8; ++j) mean2 += y[j];
            mean2 *= 0.125f;
            float var2 = 0.f;
#pragma unroll
            for (int j = 0; j < 8; ++j) { float d = y[j] - mean2; var2 = fmaf(d, d, var2); }
            var2 *= 0.125f;
            const float rs2 = rsqrtf(var2 + EPSV);

            float o[8];
#pragma unroll
            for (int j = 0; j < 8; ++j) o[j] = (y[j] - mean2) * rs2 * g2[j] + be2[j];

            const int token = blockIdx.x * 256 + g * 128 + tloc;
            float4* op = reinterpret_cast<float4*>(out + (size_t)token * NQ);
            op[0] = make_float4(o[0], o[1], o[2], o[3]);
            op[1] = make_float4(o[4], o[5], o[6], o[7]);
        }
    }
}

extern "C" void kernel_launch(void* const* d_in, const int* in_sizes, int n_in,
                              void* d_out, int out_size, void* d_ws, size_t ws_size,
                              hipStream_t stream) {
    const float* x     = (const float*)d_in[0];
    const float* theta = (const float*)d_in[1];
    const float* phi   = (const float*)d_in[2];
    const float* W1    = (const float*)d_in[3];
    const float* b1    = (const float*)d_in[4];
    const float* W2    = (const float*)d_in[5];
    const float* b2    = (const float*)d_in[6];
    const float* g1    = (const float*)d_in[7];
    const float* be1   = (const float*)d_in[8];
    const float* g2    = (const float*)d_in[9];
    const float* be2   = (const float*)d_in[10];
    float* out = (float*)d_out;

    const int ntok = in_sizes[0] / NQ;   // 65536
    const int grid = ntok / 256;         // 256 blocks x 512 thr, 1 block/CU

    qtb_kernel<<<grid, 512, 0, stream>>>(x, theta, phi, W1, b1, W2, b2,
                                         g1, be1, g2, be2, out);
}

// Round 11
// 20.559 us; speedup vs baseline: 2.2050x; 2.2050x over previous
//
#include <hip/hip_runtime.h>
#include <math.h>

#define NQ 8
#define FDIM 2048
#define EPSV 1e-5f

typedef __attribute__((ext_vector_type(8))) short short8v;   // 8 bf16 = 4 VGPR
typedef __attribute__((ext_vector_type(16))) float f32x16;   // 32x32 C/D frag

__device__ __forceinline__ unsigned pk_bf16(float lo, float hi) {
    unsigned r;
    asm("v_cvt_pk_bf16_f32 %0, %1, %2" : "=v"(r) : "v"(lo), "v"(hi));
    return r;
}

__device__ __forceinline__ short8v pack4(unsigned a, unsigned b, unsigned c, unsigned d) {
    uint4 w; w.x = a; w.y = b; w.z = c; w.w = d;
    return __builtin_bit_cast(short8v, w);
}

#define MFMA32 __builtin_amdgcn_mfma_f32_32x32x16_bf16

// packed relu (v_pk_max_f32) + bf16 repack of a C1 fragment into 2 A-frags
#define RP(C, d0, d1)                                                   \
  { const f32x16 m_ = __builtin_elementwise_max(C, zeroC);              \
    d0 = pack4(pk_bf16(m_[0],  m_[1]),  pk_bf16(m_[2],  m_[3]),         \
               pk_bf16(m_[4],  m_[5]),  pk_bf16(m_[6],  m_[7]));        \
    d1 = pack4(pk_bf16(m_[8],  m_[9]),  pk_bf16(m_[10], m_[11]),        \
               pk_bf16(m_[12], m_[13]), pk_bf16(m_[14], m_[15])); }

// R11: full-unroll body (C2IDX compile-time -> ds offsets are immediates,
// no wrap math, no phi copies). R10 diagnostic: loop=11.4us VALU-bound
// (VALUBusy 55-59 vs MfmaUtil 28-31), overhead=11us.
#define ITER(AUSE, ALOAD, B0USE, B1USE, C2IDX)                          \
  {                                                                     \
    short8v p00, p01, p10, p11;                                         \
    RP(C1_0, p00, p01); RP(C1_1, p10, p11);                             \
    C1_0 = MFMA32(AUSE, b1S0, zeroC, 0, 0, 0);                          \
    C1_1 = MFMA32(AUSE, b1S1, zeroC, 0, 0, 0);                          \
    acc0 = MFMA32(p00, B0USE, acc0, 0, 0, 0);                           \
    acc1 = MFMA32(p10, B0USE, acc1, 0, 0, 0);                           \
    acc0 = MFMA32(p01, B1USE, acc0, 0, 0, 0);                           \
    acc1 = MFMA32(p11, B1USE, acc1, 0, 0, 0);                           \
    short8v p20, p21, p30, p31;                                         \
    RP(C1_2, p20, p21); RP(C1_3, p30, p31);                             \
    C1_2 = MFMA32(AUSE, b1S2, zeroC, 0, 0, 0);                          \
    C1_3 = MFMA32(AUSE, b1S3, zeroC, 0, 0, 0);                          \
    acc2 = MFMA32(p20, B0USE, acc2, 0, 0, 0);                           \
    acc3 = MFMA32(p30, B0USE, acc3, 0, 0, 0);                           \
    acc2 = MFMA32(p21, B1USE, acc2, 0, 0, 0);                           \
    acc3 = MFMA32(p31, B1USE, acc3, 0, 0, 0);                           \
    ALOAD = *reinterpret_cast<const short8v*>(W1p + (C2IDX) * 512);     \
    B0USE = *reinterpret_cast<const short8v*>(W2p + (C2IDX) * 32);      \
    B1USE = *reinterpret_cast<const short8v*>(W2p + (C2IDX) * 32 + 16); \
  }

__launch_bounds__(512, 2)
__global__ void qtb_kernel(const float* __restrict__ x,
                           const float* __restrict__ theta,
                           const float* __restrict__ phi,
                           const float* __restrict__ W1,
                           const float* __restrict__ b1,
                           const float* __restrict__ W2,
                           const float* __restrict__ b2,
                           const float* __restrict__ g1,
                           const float* __restrict__ be1,
                           const float* __restrict__ g2,
                           const float* __restrict__ be2,
                           float* __restrict__ out)
{
    __shared__ short W1f[64 * 512];    // A-frag order, 64 KB
    __shared__ short W2s[8 * 2056];    // quad-permuted k, ~32 KB
    __shared__ float park[8][1024];    // per-wave partial f (128 tok x 8), 32 KB
    __shared__ float hLds[256 * 8];    // h parked for the epilogue, 8 KB

    const int tid  = threadIdx.x;
    const int lane = tid & 63;
    const int wid  = tid >> 6;      // 0..7
    const int g    = wid & 1;       // token half (128 tokens)
    const int q    = wid >> 1;      // f-quarter 0..3
    const int hi2  = lane >> 5;
    const int il   = lane & 31;
    const int tbase = blockIdx.x * 256 + g * 128;

    // ---- Phase A: issue x loads first (prologue depends only on these) ----
    const float4 xA0 = reinterpret_cast<const float4*>(x + (size_t)(tbase + lane) * NQ)[0];
    const float4 xA1 = reinterpret_cast<const float4*>(x + (size_t)(tbase + lane) * NQ)[1];
    const float4 xB0 = reinterpret_cast<const float4*>(x + (size_t)(tbase + 64 + lane) * NQ)[0];
    const float4 xB1 = reinterpret_cast<const float4*>(x + (size_t)(tbase + 64 + lane) * NQ)[1];

    // ---- Phase B: issue ALL staging loads into registers (latency hides
    //      under the Phase-C prologue compute) ----
    float4 w1lo[4], w1hi[4]; float bk4[4];
#pragma unroll
    for (int it = 0; it < 4; ++it) {
        const int k = tid + it * 512;
        w1lo[it] = *reinterpret_cast<const float4*>(W1 + (size_t)k * NQ);
        w1hi[it] = *reinterpret_cast<const float4*>(W1 + (size_t)k * NQ + 4);
        bk4[it]  = b1[k];
    }
    float4 w2v[8];
#pragma unroll
    for (int it = 0; it < 8; ++it) {
        const int idx = tid + it * 512;
        const int i = idx >> 9, kq = idx & 511;
        w2v[it] = *reinterpret_cast<const float4*>(W2 + (size_t)i * FDIM + kq * 4);
    }

    // ---- Phase C: per-token prologue (2 tokens per lane) ----
    float h[2][8];
    unsigned zpkt[2][4];
#pragma unroll
    for (int tt = 0; tt < 2; ++tt) {
        const float4 x0 = tt ? xB0 : xA0;
        const float4 x1 = tt ? xB1 : xA1;
        const float xv[8] = {x0.x, x0.y, x0.z, x0.w, x1.x, x1.y, x1.z, x1.w};

        float c[8];
#pragma unroll
        for (int j = 0; j < 8; ++j) c[j] = __cosf(xv[j] + theta[j]);
        float attn[8];
        attn[0] = ((c[1] * c[2]) * (c[3] * c[4])) * ((c[5] * c[6]) * c[7]);
        {
            float p = c[0];
#pragma unroll
            for (int j = 1; j < 8; ++j) { p *= c[j]; attn[j] = p; }
        }
        float s[8];
#pragma unroll
        for (int j = 0; j < 8; ++j) s[j] = xv[j] + attn[j];
        float mean = 0.f;
#pragma unroll
        for (int j = 0; j < 8; ++j) mean += s[j];
        mean *= 0.125f;
        float var = 0.f;
#pragma unroll
        for (int j = 0; j < 8; ++j) { float d = s[j] - mean; var = fmaf(d, d, var); }
        var *= 0.125f;
        const float rs = rsqrtf(var + EPSV);
#pragma unroll
        for (int j = 0; j < 8; ++j) h[tt][j] = (s[j] - mean) * rs * g1[j] + be1[j];

        float zv[8];
#pragma unroll
        for (int j = 0; j < 8; ++j) zv[j] = __cosf(phi[j]) * __cosf(h[tt][j]);
#pragma unroll
        for (int p = 0; p < 4; ++p) zpkt[tt][p] = pk_bf16(zv[2 * p], zv[2 * p + 1]);
    }

    // park h for the epilogue (distinct LDS region; safe before the barrier)
    if (q == 0) {
        float4* hp0 = reinterpret_cast<float4*>(&hLds[(g * 128 + lane) * 8]);
        hp0[0] = make_float4(h[0][0], h[0][1], h[0][2], h[0][3]);
        hp0[1] = make_float4(h[0][4], h[0][5], h[0][6], h[0][7]);
        float4* hp1 = reinterpret_cast<float4*>(&hLds[(g * 128 + 64 + lane) * 8]);
        hp1[0] = make_float4(h[1][0], h[1][1], h[1][2], h[1][3]);
        hp1[1] = make_float4(h[1][4], h[1][5], h[1][6], h[1][7]);
    }

    // z B-fragments for 4 token-subtiles
    unsigned zs[2][2][4];
#pragma unroll
    for (int tt = 0; tt < 2; ++tt)
#pragma unroll
        for (int p = 0; p < 4; ++p) {
            zs[tt][0][p] = (unsigned)__shfl((int)zpkt[tt][p], il);
            zs[tt][1][p] = (unsigned)__shfl((int)zpkt[tt][p], 32 + il);
        }
    const unsigned biasv = 0x00003f80u;  // bf16(1.0) low half
    const short8v b1S0 = pack4(hi2 ? zs[0][0][2] : zs[0][0][0],
                               hi2 ? zs[0][0][3] : zs[0][0][1],
                               hi2 ? 0u : biasv, 0u);
    const short8v b1S1 = pack4(hi2 ? zs[0][1][2] : zs[0][1][0],
                               hi2 ? zs[0][1][3] : zs[0][1][1],
                               hi2 ? 0u : biasv, 0u);
    const short8v b1S2 = pack4(hi2 ? zs[1][0][2] : zs[1][0][0],
                               hi2 ? zs[1][0][3] : zs[1][0][1],
                               hi2 ? 0u : biasv, 0u);
    const short8v b1S3 = pack4(hi2 ? zs[1][1][2] : zs[1][1][0],
                               hi2 ? zs[1][1][3] : zs[1][1][1],
                               hi2 ? 0u : biasv, 0u);

    // ---- Phase D: pack + LDS-write the staged weights, then barrier ----
#pragma unroll
    for (int it = 0; it < 4; ++it) {
        const int k = tid + it * 512;
        uint4 d0, d1;
        d0.x = pk_bf16(w1lo[it].x, w1lo[it].y); d0.y = pk_bf16(w1lo[it].z, w1lo[it].w);
        d0.z = pk_bf16(bk4[it], 0.f);           d0.w = 0u;
        d1.x = pk_bf16(w1hi[it].x, w1hi[it].y); d1.y = pk_bf16(w1hi[it].z, w1hi[it].w);
        d1.z = 0u;                              d1.w = 0u;
        *reinterpret_cast<uint4*>(&W1f[(k >> 5) * 512 + (k & 31) * 8])        = d0;
        *reinterpret_cast<uint4*>(&W1f[(k >> 5) * 512 + ((k & 31) + 32) * 8]) = d1;
    }
#pragma unroll
    for (int it = 0; it < 8; ++it) {
        const int idx = tid + it * 512;
        const int i = idx >> 9, kq = idx & 511;
        const int k0 = kq * 4;
        const int quad = (k0 >> 2) & 3;
        const int posq = (0x3120 >> (quad * 4)) & 0xF;   // 0->0,1->2,2->1,3->3
        const int dcol = (k0 & ~15) | (posq * 4);
        uint2 pkw; pkw.x = pk_bf16(w2v[it].x, w2v[it].y); pkw.y = pk_bf16(w2v[it].z, w2v[it].w);
        *reinterpret_cast<uint2*>(&W2s[i * 2056 + dcol]) = pkw;
    }
    __syncthreads();

    // ---- k-loop: 16 chunks, FULLY UNROLLED (immediates, no bookkeeping) ----
    f32x16 zeroC;
#pragma unroll
    for (int e = 0; e < 16; ++e) zeroC[e] = 0.f;
    f32x16 acc0 = zeroC, acc1 = zeroC, acc2 = zeroC, acc3 = zeroC;

    const int ir = il & 7;
    const short* W1p = &W1f[(q * 16) * 512 + lane * 8];          // + t*512 (imm)
    const short* W2p = &W2s[ir * 2056 + (q * 16) * 32 + hi2 * 8]; // + t*32 (imm)

    short8v A1a = *reinterpret_cast<const short8v*>(W1p);
    short8v B0a = *reinterpret_cast<const short8v*>(W2p);
    short8v B1a = *reinterpret_cast<const short8v*>(W2p + 16);
    f32x16 C1_0 = MFMA32(A1a, b1S0, zeroC, 0, 0, 0);
    f32x16 C1_1 = MFMA32(A1a, b1S1, zeroC, 0, 0, 0);
    f32x16 C1_2 = MFMA32(A1a, b1S2, zeroC, 0, 0, 0);
    f32x16 C1_3 = MFMA32(A1a, b1S3, zeroC, 0, 0, 0);
    short8v A1b = *reinterpret_cast<const short8v*>(W1p + 512);
    short8v B0b = *reinterpret_cast<const short8v*>(W2p + 32);
    short8v B1b = *reinterpret_cast<const short8v*>(W2p + 32 + 16);

#pragma unroll
    for (int t = 0; t < 16; t += 2) {
        ITER(A1b, A1a, B0a, B1a, (t + 2) & 15);   // compile-time indices
        ITER(A1a, A1b, B0b, B1b, (t + 3) & 15);
    }

    // ---- park partial f (cols<8), 2-way-free bank pattern ----
    if (il < 8) {
        float* fb = &park[wid][0];
#pragma unroll
        for (int r = 0; r < 16; ++r) {
            const int trow = (r & 3) + 8 * (r >> 2) + 4 * hi2;
            fb[trow * 8 + il]         = acc0[r];
            fb[(32 + trow) * 8 + il]  = acc1[r];
            fb[(64 + trow) * 8 + il]  = acc2[r];
            fb[(96 + trow) * 8 + il]  = acc3[r];
        }
    }
    __syncthreads();

    // ---- combine + LN2 + store: waves q==0, 2 tokens per lane ----
    if (q == 0) {
#pragma unroll
        for (int tt = 0; tt < 2; ++tt) {
            const int tloc = tt * 64 + lane;
            float fv[8] = {0.f, 0.f, 0.f, 0.f, 0.f, 0.f, 0.f, 0.f};
#pragma unroll
            for (int qq = 0; qq < 4; ++qq) {
                const float* pb = &park[qq * 2 + g][tloc * 8];
                const float4 f0 = *reinterpret_cast<const float4*>(pb);
                const float4 f1 = *reinterpret_cast<const float4*>(pb + 4);
                fv[0] += f0.x; fv[1] += f0.y; fv[2] += f0.z; fv[3] += f0.w;
                fv[4] += f1.x; fv[5] += f1.y; fv[6] += f1.z; fv[7] += f1.w;
            }

            const float4 h0 = reinterpret_cast<const float4*>(&hLds[(g * 128 + tloc) * 8])[0];
            const float4 h1 = reinterpret_cast<const float4*>(&hLds[(g * 128 + tloc) * 8])[1];
            const float hv[8] = {h0.x, h0.y, h0.z, h0.w, h1.x, h1.y, h1.z, h1.w};

            float y[8];
#pragma unroll
            for (int j = 0; j < 8; ++j) y[j] = hv[j] + fv[j] + b2[j];
            float mean2 = 0.f;
#pragma unroll
            for (int j = 0; j < 8; ++j) mean2 += y[j];
            mean2 *= 0.125f;
            float var2 = 0.f;
#pragma unroll
            for (int j = 0; j < 8; ++j) { float d = y[j] - mean2; var2 = fmaf(d, d, var2); }
            var2 *= 0.125f;
            const float rs2 = rsqrtf(var2 + EPSV);

            float o[8];
#pragma unroll
            for (int j = 0; j < 8; ++j) o[j] = (y[j] - mean2) * rs2 * g2[j] + be2[j];

            const int token = blockIdx.x * 256 + g * 128 + tloc;
            float4* op = reinterpret_cast<float4*>(out + (size_t)token * NQ);
            op[0] = make_float4(o[0], o[1], o[2], o[3]);
            op[1] = make_float4(o[4], o[5], o[6], o[7]);
        }
    }
}

extern "C" void kernel_launch(void* const* d_in, const int* in_sizes, int n_in,
                              void* d_out, int out_size, void* d_ws, size_t ws_size,
                              hipStream_t stream) {
    const float* x     = (const float*)d_in[0];
    const float* theta = (const float*)d_in[1];
    const float* phi   = (const float*)d_in[2];
    const float* W1    = (const float*)d_in[3];
    const float* b1    = (const float*)d_in[4];
    const float* W2    = (const float*)d_in[5];
    const float* b2    = (const float*)d_in[6];
    const float* g1    = (const float*)d_in[7];
    const float* be1   = (const float*)d_in[8];
    const float* g2    = (const float*)d_in[9];
    const float* be2   = (const float*)d_in[10];
    float* out = (float*)d_out;

    const int ntok = in_sizes[0] / NQ;   // 65536
    const int grid = ntok / 256;         // 256 blocks x 512 thr, 1 block/CU

    qtb_kernel<<<grid, 512, 0, stream>>>(x, theta, phi, W1, b1, W2, b2,
                                         g1, be1, g2, be2, out);
}